// Round 7
// baseline (367.657 us; speedup 1.0000x reference)
//
#include <hip/hip_runtime.h>
#include <hip/hip_bf16.h>

// O[b,i,h,p] = sum_{c=l*3+j in 768, tap in 3} W[l,j,tap,i] * S_{b,h}[c][p+tap]
// S[c][t]: t=0,8,9 -> 0; t=(w+1)%7+1 <- V[c][w]
// V[c][w] = x[b,l,r1,w]*[0<=r1<7] + x[b,256+l,r2,w]*[0<=r2<7],
//   r1 = h+j-1, r2 = ((h+6)%7)+j-1            (verified rounds 1-2)
//
// Round 3: Vt[bh][t][c] bf16 (77 MB) in d_ws.  R7: gload_lds dbuf 154us.
// R8 counted-vmcnt: NULL. R9 256x128 tile: REGRESSED (3.5 blk/CU imbalance).
// Budget: LDS pipe ~82% busy (128 x 1KB ops/block-chunk) is the binding pipe.
// Round 10: B never touches LDS. prep_wf emits W2 in MFMA-fragment order
//   (W2f[nb][chunk][tap][wn*4+nf][lane]x16B) so each B-frag is ONE coalesced
//   1KB dwordx4 load from L2 (W2f = 2.36MB, L2-resident). LDS ops/block-chunk
//   128 -> 56; LDS 14.5KB; geometry back to R7 (grid 1792 = 7 blk/CU exact).

typedef __bf16 bf16x8 __attribute__((ext_vector_type(8)));
typedef float f32x4 __attribute__((ext_vector_type(4)));
typedef unsigned int u32;

#define VT_OFFSET (4u << 20)                       // W2f at d_ws+0, Vt at d_ws+4MB
#define VT_BYTES  (7168ull * 7 * 768 * 2)          // 77,070,336
#define WS_NEED   (VT_OFFSET + VT_BYTES)

__device__ __forceinline__ void gload_lds16(const void* g, void* l) {
    __builtin_amdgcn_global_load_lds(
        (const __attribute__((address_space(1))) u32*)g,
        (__attribute__((address_space(3))) u32*)l, 16, 0, 0);
}

// ---- prep_wf: Wg[(c*3+tap)*512 + i] -> W2f fragment layout ----
// unit(nb,chunk,tap,wnf,gq,l15) = (((nb*24+chunk)*3+tap)*8 + wnf)*64 + gq*16 + l15
// holds bf16x8 = W2[i = nb*128+wnf*16+l15][col = tap*768 + chunk*32 + gq*8 ..+7]
__global__ __launch_bounds__(256) void prep_wf(const float* __restrict__ Wg,
                                               __bf16* __restrict__ W2f) {
    __shared__ float ws_[96][65];                  // +1 pad
    const int kt = blockIdx.x % 24;                // = chunk
    const int it_ = blockIdx.x / 24;
    const int K0 = kt * 96;
    const int I0 = it_ * 64;
    const int tid = threadIdx.x;

    #pragma unroll
    for (int t = 0; t < 6; ++t) {
        const int u = t * 256 + tid;
        const int row = u >> 4;
        const int f4 = u & 15;
        const float4 v = *(const float4*)(Wg + (size_t)(K0 + row) * 512 + I0 + f4 * 4);
        ws_[row][f4 * 4 + 0] = v.x;
        ws_[row][f4 * 4 + 1] = v.y;
        ws_[row][f4 * 4 + 2] = v.z;
        ws_[row][f4 * 4 + 3] = v.w;
    }
    __syncthreads();

    // 768 units: u -> (q = u/192, tap = (u/64)%3, i_loc = u%64); consecutive
    // tid -> consecutive i_loc -> consecutive units (256B coalesced runs).
    #pragma unroll
    for (int t = 0; t < 3; ++t) {
        const int u = t * 256 + tid;
        const int q = u / 192;
        const int tap = (u / 64) % 3;
        const int i_loc = u & 63;
        bf16x8 o;
        #pragma unroll
        for (int e = 0; e < 8; ++e)
            o[e] = (__bf16)ws_[3 * (q * 8 + e) + tap][i_loc];
        const int i_g = I0 + i_loc;
        const int nb = i_g >> 7;
        const int r = i_g & 127;
        const int wnf = r >> 4;                    // wn*4+nf
        const int l15 = r & 15;
        const int unit = (((nb * 24 + kt) * 3 + tap) * 8 + wnf) * 64 + q * 16 + l15;
        *(bf16x8*)(W2f + (size_t)unit * 8) = o;
    }
}

// ---- prep_w (old [i][tap][c] layout) for the fallback path only ----
__global__ __launch_bounds__(256) void prep_w(const float* __restrict__ Wg,
                                              __bf16* __restrict__ W2) {
    __shared__ float ws_[96][65];
    const int kt = blockIdx.x % 24;
    const int it_ = blockIdx.x / 24;
    const int K0 = kt * 96;
    const int I0 = it_ * 64;
    const int tid = threadIdx.x;

    #pragma unroll
    for (int t = 0; t < 6; ++t) {
        const int u = t * 256 + tid;
        const int row = u >> 4;
        const int f4 = u & 15;
        const float4 v = *(const float4*)(Wg + (size_t)(K0 + row) * 512 + I0 + f4 * 4);
        ws_[row][f4 * 4 + 0] = v.x;
        ws_[row][f4 * 4 + 1] = v.y;
        ws_[row][f4 * 4 + 2] = v.z;
        ws_[row][f4 * 4 + 3] = v.w;
    }
    __syncthreads();

    #pragma unroll
    for (int t = 0; t < 3; ++t) {
        const int u = t * 256 + tid;
        const int i = u / 12;
        const int rem = u - i * 12;
        const int tap = rem >> 2;
        const int q = rem & 3;
        bf16x8 o;
        #pragma unroll
        for (int e = 0; e < 8; ++e)
            o[e] = (__bf16)ws_[3 * (q * 8 + e) + tap][i];
        *(bf16x8*)(W2 + (size_t)(I0 + i) * 2304 + tap * 768 + 32 * kt + q * 8) = o;
    }
}

// Block per (b, g) with g = channel-half.
__global__ __launch_bounds__(256) void prep_v(const float* __restrict__ x,
                                              __bf16* __restrict__ Vt) {
    __shared__ float xs[256 * 49];
    const int b = blockIdx.x >> 1;
    const int g = blockIdx.x & 1;
    const int tid = threadIdx.x;

    {
        const float4* src0 = (const float4*)(x + ((size_t)b * 512 + g * 128) * 49);
        const float4* src1 = (const float4*)(x + ((size_t)b * 512 + 256 + g * 128) * 49);
        float4* dst0 = (float4*)xs;
        float4* dst1 = (float4*)(xs + 128 * 49);
        #pragma unroll
        for (int it = 0; it < 7; ++it) {
            const int q = it * 256 + tid;
            if (q < 1568) dst0[q] = src0[q];
        }
        #pragma unroll
        for (int it = 0; it < 7; ++it) {
            const int q = it * 256 + tid;
            if (q < 1568) dst1[q] = src1[q];
        }
    }
    __syncthreads();

    for (int h = 0; h < 7; ++h) {
        const int hm = (h + 6) % 7;
        for (int it = 0; it < 2; ++it) {
            const int u = it * 256 + tid;
            if (u < 336) {
                const int r = u / 48;
                const int k = u - r * 48;
                const int w = (r + 6) % 7;
                bf16x8 vv;
                #pragma unroll
                for (int e = 0; e < 8; ++e) {
                    const int c = k * 8 + e;
                    const int l = c / 3;
                    const int j = c - 3 * l;
                    const int r1 = h + j - 1;
                    const int r2 = hm + j - 1;
                    float v = 0.f;
                    if (r1 >= 0 && r1 < 7) v += xs[l * 49 + r1 * 7 + w];
                    if (r2 >= 0 && r2 < 7) v += xs[(128 + l) * 49 + r2 * 7 + w];
                    vv[e] = (__bf16)v;
                }
                *(bf16x8*)(Vt + (size_t)((b * 7 + h) * 7 + r) * 768 + g * 384 + k * 8) = vv;
            }
        }
    }
}

// ---- gemm_vt v5: T via gload_lds dbuf; B direct-from-L2 (fragment layout) ----
// LDS: T0 [0,7168) Z0 [7168,7232) T1 [7232,14400) Z1 [14400,14464)
// T buffer: [16 bh][7 ct][4 slot x 16B]; slot qs holds source q = qs^(ct&3).
__global__ __launch_bounds__(256, 2) void gemm_vt(const __bf16* __restrict__ Vt,
                                                  const __bf16* __restrict__ W2f,
                                                  float* __restrict__ out) {
    __shared__ __align__(1024) char L[14464];

    const int tid = threadIdx.x;
    const int g0 = blockIdx.x;                     // grid 1792 = 448 mb x 4 nb
    const int nb = (g0 >> 3) & 3;
    const int mb = ((g0 >> 5) << 3) | (g0 & 7);    // 0..447

    // zero rows (one per T buffer), once
    if (tid < 32) {
        const int off = (tid < 16) ? 7168 + tid * 4 : 14400 + (tid - 16) * 4;
        *(int*)(L + off) = 0;
    }

    // ---- T-stage per-lane source offsets (448 units of 16B) ----
    int tsrc[2]; bool tok[2];
    #pragma unroll
    for (int it = 0; it < 2; ++it) {
        const int u = it * 256 + tid;
        tok[it] = (u < 448);
        const int bh = u / 28;
        const int rem = u - bh * 28;
        const int ct = rem >> 2;
        const int qs = rem & 3;
        const int q = qs ^ (ct & 3);               // slot qs holds source q
        tsrc[it] = ((mb * 16 + bh) * 7 + ct) * 1536 + q * 16;
    }

    const int lane = tid & 63;
    const int wave = tid >> 6;
    const int wm = wave >> 1;                      // 2x2 wave grid, each 64x64
    const int wn = wave & 1;
    const int ln15 = lane & 15;
    const int gq = lane >> 4;

    // ---- B-frag byte offsets into W2f (chunk-/tap-invariant part) ----
    // addr = base + chunk*24576 + tap*8192 + boff[nf]
    int boff[4];
    #pragma unroll
    for (int nf = 0; nf < 4; ++nf)
        boff[nf] = nb * 589824 + (wn * 4 + nf) * 1024 + lane * 16;

    // ---- chunk-invariant A read offsets (relative to T buffer base) ----
    int afoff[3][4];
    #pragma unroll
    for (int tap = 0; tap < 3; ++tap) {
        #pragma unroll
        for (int mf = 0; mf < 4; ++mf) {
            const int bh_l = wm * 8 + mf * 2 + (ln15 >> 3);
            const int p = ln15 & 7;
            const int ct = p + tap - 1;
            afoff[tap][mf] = (ct >= 0 && ct <= 6)
                ? bh_l * 448 + ct * 64 + ((gq ^ (ct & 3)) * 16)
                : 7168;                            // zero row (broadcast)
        }
    }

    f32x4 acc[4][4];
    #pragma unroll
    for (int a = 0; a < 4; ++a)
        #pragma unroll
        for (int bq = 0; bq < 4; ++bq) acc[a][bq] = (f32x4){0.f, 0.f, 0.f, 0.f};

    const char* VtB = (const char*)Vt;
    const char* W2fB = (const char*)W2f;

    // prologue: stage chunk 0 -> T buffer 0
    {
        const char* vb = VtB;
        if (tok[0]) gload_lds16(vb + tsrc[0], L + tid * 16);
        if (tok[1]) gload_lds16(vb + tsrc[1], L + 4096 + tid * 16);
    }
    __syncthreads();

    for (int chunk = 0; chunk < 24; ++chunk) {
        const int cur = chunk & 1;
        // prefetch next T chunk (flies under B loads + MFMAs; drained by the
        // end-of-chunk __syncthreads)
        if (chunk < 23) {
            const char* vb = VtB + (chunk + 1) * 64;
            char* td = L + (cur ^ 1) * 7232;
            if (tok[0]) gload_lds16(vb + tsrc[0], td + tid * 16);
            if (tok[1]) gload_lds16(vb + tsrc[1], td + 4096 + tid * 16);
        }

        // B-frags straight from L2 (coalesced 1KB each); issue all 12 early
        const char* wb = W2fB + chunk * 24576;
        bf16x8 bfr[3][4];
        #pragma unroll
        for (int tap = 0; tap < 3; ++tap)
            #pragma unroll
            for (int nf = 0; nf < 4; ++nf)
                bfr[tap][nf] = *(const bf16x8*)(wb + tap * 8192 + boff[nf]);

        const char* Tb = L + cur * 7232;
        #pragma unroll
        for (int tap = 0; tap < 3; ++tap) {
            bf16x8 af[4];
            #pragma unroll
            for (int mf = 0; mf < 4; ++mf)
                af[mf] = *(const bf16x8*)(Tb + afoff[tap][mf]);
            #pragma unroll
            for (int mf = 0; mf < 4; ++mf)
                #pragma unroll
                for (int nf = 0; nf < 4; ++nf)
                    acc[mf][nf] = __builtin_amdgcn_mfma_f32_16x16x32_bf16(
                        af[mf], bfr[tap][nf], acc[mf][nf], 0, 0, 0);
        }

        __syncthreads();       // reads of buf[cur] done; prefetch landed
    }

    // ---- epilogue: D row = gq*4+r, col = lane&15 ----
    #pragma unroll
    for (int mf = 0; mf < 4; ++mf) {
        #pragma unroll
        for (int r = 0; r < 4; ++r) {
            const int mrow = gq * 4 + r;
            const int Mg_l = wm * 64 + mf * 16 + mrow;
            const int p = Mg_l & 7;
            if (p == 7) continue;                  // padded row
            const int bh_l = Mg_l >> 3;
            const int bhg = mb * 16 + bh_l;
            const int b = bhg / 7;
            const int h = bhg - 7 * b;
            #pragma unroll
            for (int nf = 0; nf < 4; ++nf) {
                const int i = nb * 128 + wn * 64 + nf * 16 + ln15;
                out[(((size_t)b * 512 + i) * 7 + h) * 7 + p] = acc[mf][nf][r];
            }
        }
    }
}

// ---------------- fallback (round-2 implicit staging) if ws is small --------
__global__ __launch_bounds__(256) void gemm_shift(const float* __restrict__ x,
                                                  const __bf16* __restrict__ W2,
                                                  float* __restrict__ out) {
    __shared__ __bf16 T[16 * 10 * 40];
    __shared__ __bf16 Bt[128 * 104];

    const int tid = threadIdx.x;
    const int mb = blockIdx.x >> 2;
    const int nb = blockIdx.x & 3;
    const int i0 = nb * 128;

    const int cl  = tid & 31;
    const int bh0 = tid >> 5;
    const int bhg0 = mb * 16 + bh0;
    const int bhg1 = bhg0 + 8;
    const int b0 = bhg0 / 7, h0 = bhg0 - 7 * b0;
    const int b1 = bhg1 / 7, h1 = bhg1 - 7 * b1;
    const int hm0 = (h0 + 6) % 7, hm1 = (h1 + 6) % 7;

    for (int q = tid; q < 16 * 10 * 40 / 2; q += 256) ((int*)T)[q] = 0;

    const int lane = tid & 63;
    const int wave = tid >> 6;
    const int wm = wave >> 1;
    const int wn = wave & 1;
    const int ln15 = lane & 15;
    const int gq = lane >> 4;

    f32x4 acc[4][4];
    #pragma unroll
    for (int a = 0; a < 4; ++a)
        #pragma unroll
        for (int bq = 0; bq < 4; ++bq) acc[a][bq] = (f32x4){0.f, 0.f, 0.f, 0.f};

    __syncthreads();

    for (int chunk = 0; chunk < 24; ++chunk) {
        const int cg = chunk * 32 + cl;
        const int l = cg / 3;
        const int j = cg - 3 * l;
        {
            const int r1 = h0 + j - 1, r2 = hm0 + j - 1;
            float v[7] = {0.f, 0.f, 0.f, 0.f, 0.f, 0.f, 0.f};
            if (r1 >= 0 && r1 < 7) {
                const float* p1 = x + (((size_t)b0 * 512 + l) * 7 + r1) * 7;
                #pragma unroll
                for (int w = 0; w < 7; ++w) v[w] += p1[w];
            }
            if (r2 >= 0 && r2 < 7) {
                const float* p2 = x + (((size_t)b0 * 512 + 256 + l) * 7 + r2) * 7;
                #pragma unroll
                for (int w = 0; w < 7; ++w) v[w] += p2[w];
            }
            #pragma unroll
            for (int w = 0; w < 7; ++w)
                T[bh0 * 400 + ((w + 1) % 7 + 1) * 40 + cl] = (__bf16)v[w];
        }
        {
            const int r1 = h1 + j - 1, r2 = hm1 + j - 1;
            float v[7] = {0.f, 0.f, 0.f, 0.f, 0.f, 0.f, 0.f};
            if (r1 >= 0 && r1 < 7) {
                const float* p1 = x + (((size_t)b1 * 512 + l) * 7 + r1) * 7;
                #pragma unroll
                for (int w = 0; w < 7; ++w) v[w] += p1[w];
            }
            if (r2 >= 0 && r2 < 7) {
                const float* p2 = x + (((size_t)b1 * 512 + 256 + l) * 7 + r2) * 7;
                #pragma unroll
                for (int w = 0; w < 7; ++w) v[w] += p2[w];
            }
            #pragma unroll
            for (int w = 0; w < 7; ++w)
                T[(bh0 + 8) * 400 + ((w + 1) % 7 + 1) * 40 + cl] = (__bf16)v[w];
        }

        #pragma unroll
        for (int it = 0; it < 6; ++it) {
            const int u = it * 256 + tid;
            const int tap = u >> 9;
            const int rem = u & 511;
            const int n = rem >> 2;
            const int q = rem & 3;
            const float4 val = *(const float4*)(W2 + (size_t)(i0 + n) * 2304 +
                                                tap * 768 + chunk * 32 + q * 8);
            *(float4*)(&Bt[n * 104 + tap * 32 + q * 8]) = val;
        }

        __syncthreads();

        #pragma unroll
        for (int tap = 0; tap < 3; ++tap) {
            bf16x8 af[4], bfr[4];
            #pragma unroll
            for (int mf = 0; mf < 4; ++mf) {
                const int bh_l = wm * 8 + mf * 2 + (ln15 >> 3);
                const int p = ln15 & 7;
                af[mf] = *(const bf16x8*)(&T[(bh_l * 10 + p + tap) * 40 + gq * 8]);
            }
            #pragma unroll
            for (int nf = 0; nf < 4; ++nf) {
                const int n_l = wn * 64 + nf * 16 + ln15;
                bfr[nf] = *(const bf16x8*)(&Bt[n_l * 104 + tap * 32 + gq * 8]);
            }
            #pragma unroll
            for (int mf = 0; mf < 4; ++mf)
                #pragma unroll
                for (int nf = 0; nf < 4; ++nf)
                    acc[mf][nf] = __builtin_amdgcn_mfma_f32_16x16x32_bf16(
                        af[mf], bfr[nf], acc[mf][nf], 0, 0, 0);
        }

        __syncthreads();
    }

    #pragma unroll
    for (int mf = 0; mf < 4; ++mf) {
        #pragma unroll
        for (int r = 0; r < 4; ++r) {
            const int mrow = gq * 4 + r;
            const int Mg_l = wm * 64 + mf * 16 + mrow;
            const int p = Mg_l & 7;
            if (p == 7) continue;
            const int bh_l = Mg_l >> 3;
            const int bhg = mb * 16 + bh_l;
            const int b = bhg / 7;
            const int h = bhg - 7 * b;
            #pragma unroll
            for (int nf = 0; nf < 4; ++nf) {
                const int i = i0 + wn * 64 + nf * 16 + ln15;
                out[(((size_t)b * 512 + i) * 7 + h) * 7 + p] = acc[mf][nf][r];
            }
        }
    }
}

extern "C" void kernel_launch(void* const* d_in, const int* in_sizes, int n_in,
                              void* d_out, int out_size, void* d_ws, size_t ws_size,
                              hipStream_t stream) {
    const float* x  = (const float*)d_in[0];   // (1024,512,7,7) fp32
    const float* Wg = (const float*)d_in[1];   // (256,3,3,512) fp32
    float* out = (float*)d_out;                // (1024,512,7,7) fp32

    if (ws_size >= WS_NEED) {
        __bf16* W2f = (__bf16*)d_ws;           // fragment-order W2, 2.36 MB
        __bf16* Vt = (__bf16*)((char*)d_ws + VT_OFFSET);
        prep_wf<<<dim3(192), dim3(256), 0, stream>>>(Wg, W2f);
        prep_v<<<dim3(2048), dim3(256), 0, stream>>>(x, Vt);
        gemm_vt<<<dim3(448 * 4), dim3(256), 0, stream>>>(Vt, W2f, out);
    } else {
        __bf16* W2 = (__bf16*)d_ws;            // old [i][tap][c] layout
        prep_w<<<dim3(192), dim3(256), 0, stream>>>(Wg, W2);
        gemm_shift<<<dim3(448 * 4), dim3(256), 0, stream>>>(x, W2, out);
    }
}